// Round 1
// baseline (40130.875 us; speedup 1.0000x reference)
//
#include <hip/hip_runtime.h>
#include <math.h>

// ---------------- problem constants ----------------
#define DEPTH 12
#define BSZ   64
#define T     197
#define NP    196
#define DIM   768
#define NH    12
#define HD    64
#define FFD   3072
#define NC    1000
#define NTOK  (BSZ * T)     // 12608
#define NPATCH (BSZ * NP)   // 12544

// ---------------- helpers ----------------
__device__ __forceinline__ float4 ldg4(const float* p) {
    return *reinterpret_cast<const float4*>(p);
}
__device__ __forceinline__ float wave_sum(float v) {
#pragma unroll
    for (int off = 32; off >= 1; off >>= 1) v += __shfl_xor(v, off);
    return v;
}
__device__ __forceinline__ float wave_max(float v) {
#pragma unroll
    for (int off = 32; off >= 1; off >>= 1) v = fmaxf(v, __shfl_xor(v, off));
    return v;
}

// ---------------- tiled fp32 GEMM ----------------
// C[M,N] = A[M,K] @ W[K,N] (+bias, +res, +gelu per EPI)
// 128x128 tile, BK=8, 256 threads, 8x8 micro-tile (4+4 split for bank-free LDS reads)
#define BM 128
#define BN 128
#define BK 8

__device__ __forceinline__ float4 load_b_guard(const float* wp, int ncol0, int N) {
    float4 r;
    r.x = (ncol0 + 0 < N) ? wp[0] : 0.f;
    r.y = (ncol0 + 1 < N) ? wp[1] : 0.f;
    r.z = (ncol0 + 2 < N) ? wp[2] : 0.f;
    r.w = (ncol0 + 3 < N) ? wp[3] : 0.f;
    return r;
}

template <int EPI>  // 0: +bias   1: +bias+res   2: +bias then exact gelu
__global__ __launch_bounds__(256, 2) void gemm_k(
    const float* __restrict__ A, const float* __restrict__ W,
    const float* __restrict__ bias, const float* res, float* C,
    int M, int N, int K)
{
    __shared__ float As[BK][BM];
    __shared__ float Bs[BK][BN];
    const int tid = threadIdx.x;
    const int m0 = blockIdx.x * BM, n0 = blockIdx.y * BN;
    const int tx = tid & 15, ty = tid >> 4;
    const int arow = tid >> 1, ak = (tid & 1) * 4;
    const int brow = tid >> 5, bcol = (tid & 31) * 4;
    const bool aval = (m0 + arow) < M;
    const float* Ap = A + (size_t)(m0 + arow) * K + ak;
    const float* Wp = W + (size_t)brow * N + n0 + bcol;
    const bool bfull = (n0 + BN) <= N;

    float acc[8][8];
#pragma unroll
    for (int i = 0; i < 8; i++)
#pragma unroll
        for (int j = 0; j < 8; j++) acc[i][j] = 0.f;

    float4 ar = aval ? ldg4(Ap) : make_float4(0.f, 0.f, 0.f, 0.f);
    float4 br = bfull ? ldg4(Wp) : load_b_guard(Wp, n0 + bcol, N);

    int k0 = 0;
    while (true) {
        __syncthreads();
        As[ak + 0][arow] = ar.x;
        As[ak + 1][arow] = ar.y;
        As[ak + 2][arow] = ar.z;
        As[ak + 3][arow] = ar.w;
        *reinterpret_cast<float4*>(&Bs[brow][bcol]) = br;
        __syncthreads();
        const int kn = k0 + BK;
        const bool more = kn < K;
        if (more) {
            ar = aval ? ldg4(Ap + kn) : make_float4(0.f, 0.f, 0.f, 0.f);
            const float* wp = Wp + (size_t)kn * N;
            br = bfull ? ldg4(wp) : load_b_guard(wp, n0 + bcol, N);
        }
#pragma unroll
        for (int kk = 0; kk < BK; kk++) {
            float a[8], b[8];
            *reinterpret_cast<float4*>(&a[0]) = *reinterpret_cast<const float4*>(&As[kk][ty * 4]);
            *reinterpret_cast<float4*>(&a[4]) = *reinterpret_cast<const float4*>(&As[kk][64 + ty * 4]);
            *reinterpret_cast<float4*>(&b[0]) = *reinterpret_cast<const float4*>(&Bs[kk][tx * 4]);
            *reinterpret_cast<float4*>(&b[4]) = *reinterpret_cast<const float4*>(&Bs[kk][64 + tx * 4]);
#pragma unroll
            for (int i = 0; i < 8; i++)
#pragma unroll
                for (int j = 0; j < 8; j++) acc[i][j] += a[i] * b[j];
        }
        if (!more) break;
        k0 = kn;
    }

#pragma unroll
    for (int i = 0; i < 8; i++) {
        const int m = m0 + (i < 4 ? ty * 4 + i : 64 + ty * 4 + (i - 4));
        if (m >= M) continue;
#pragma unroll
        for (int j = 0; j < 8; j++) {
            const int n = n0 + (j < 4 ? tx * 4 + j : 64 + tx * 4 + (j - 4));
            if (n >= N) continue;
            float v = acc[i][j] + bias[n];
            if (EPI == 1) v += res[(size_t)m * N + n];
            if (EPI == 2) v = 0.5f * v * (1.f + erff(v * 0.70710678118654752f));
            C[(size_t)m * N + n] = v;
        }
    }
}

// ---------------- patch-embed GEMM (gathers patchified pixels as A) ----------------
// A row r = (b, p): A[r, c] = img[b, c/256, (p/14)*16 + (c/16)%16, (p%14)*16 + c%16]
// writes X[b*197 + 1 + p, n] = acc + patch_b[n] + pos_embed[1+p, n]
__global__ __launch_bounds__(256, 2) void patch_gemm_k(
    const float* __restrict__ img, const float* __restrict__ W,
    const float* __restrict__ bias, const float* __restrict__ pos,
    float* __restrict__ X)
{
    __shared__ float As[BK][BM];
    __shared__ float Bs[BK][BN];
    const int tid = threadIdx.x;
    const int m0 = blockIdx.x * BM, n0 = blockIdx.y * BN;
    const int tx = tid & 15, ty = tid >> 4;
    const int arow = tid >> 1, ak = (tid & 1) * 4;
    const int brow = tid >> 5, bcol = (tid & 31) * 4;
    const int N = DIM, K = DIM;

    const int r = m0 + arow;           // < 12544 always (12544 % 128 == 0)
    const int b = r / NP, p = r % NP;
    const int gy = p / 14, gx = p % 14;
    const float* xb = img + (size_t)b * 3 * 224 * 224 + (size_t)(gy * 16) * 224 + gx * 16;
    const float* Wp = W + (size_t)brow * N + n0 + bcol;

    float acc[8][8];
#pragma unroll
    for (int i = 0; i < 8; i++)
#pragma unroll
        for (int j = 0; j < 8; j++) acc[i][j] = 0.f;

    int c = ak;
    float4 ar = ldg4(xb + (size_t)(c >> 8) * 50176 + ((c >> 4) & 15) * 224 + (c & 15));
    float4 br = ldg4(Wp);

    int k0 = 0;
    while (true) {
        __syncthreads();
        As[ak + 0][arow] = ar.x;
        As[ak + 1][arow] = ar.y;
        As[ak + 2][arow] = ar.z;
        As[ak + 3][arow] = ar.w;
        *reinterpret_cast<float4*>(&Bs[brow][bcol]) = br;
        __syncthreads();
        const int kn = k0 + BK;
        const bool more = kn < K;
        if (more) {
            c = kn + ak;
            ar = ldg4(xb + (size_t)(c >> 8) * 50176 + ((c >> 4) & 15) * 224 + (c & 15));
            br = ldg4(Wp + (size_t)kn * N);
        }
#pragma unroll
        for (int kk = 0; kk < BK; kk++) {
            float a[8], b2[8];
            *reinterpret_cast<float4*>(&a[0]) = *reinterpret_cast<const float4*>(&As[kk][ty * 4]);
            *reinterpret_cast<float4*>(&a[4]) = *reinterpret_cast<const float4*>(&As[kk][64 + ty * 4]);
            *reinterpret_cast<float4*>(&b2[0]) = *reinterpret_cast<const float4*>(&Bs[kk][tx * 4]);
            *reinterpret_cast<float4*>(&b2[4]) = *reinterpret_cast<const float4*>(&Bs[kk][64 + tx * 4]);
#pragma unroll
            for (int i = 0; i < 8; i++)
#pragma unroll
                for (int j = 0; j < 8; j++) acc[i][j] += a[i] * b2[j];
        }
        if (!more) break;
        k0 = kn;
    }

#pragma unroll
    for (int i = 0; i < 8; i++) {
        const int m = m0 + (i < 4 ? ty * 4 + i : 64 + ty * 4 + (i - 4));
        const int b2 = m / NP, p2 = m % NP;
        const size_t orow = (size_t)b2 * T + 1 + p2;
#pragma unroll
        for (int j = 0; j < 8; j++) {
            const int n = n0 + (j < 4 ? tx * 4 + j : 64 + tx * 4 + (j - 4));
            X[orow * DIM + n] = acc[i][j] + bias[n] + pos[(size_t)(1 + p2) * DIM + n];
        }
    }
}

// ---------------- CLS row init ----------------
__global__ void clspos_k(float* __restrict__ X, const float* __restrict__ cls,
                         const float* __restrict__ pos)
{
    const int i = blockIdx.x * 256 + threadIdx.x;
    if (i < BSZ * DIM) {
        const int b = i / DIM, d = i % DIM;
        X[(size_t)b * T * DIM + d] = cls[d] + pos[d];
    }
}

// ---------------- LayerNorm (wave per row) ----------------
__global__ __launch_bounds__(256) void ln_k(const float* __restrict__ X,
    const float* __restrict__ g, const float* __restrict__ be,
    float* __restrict__ Y, int rows, size_t xstride)
{
    const int w = threadIdx.x >> 6, lane = threadIdx.x & 63;
    const int row = (blockIdx.x << 2) + w;
    if (row >= rows) return;
    const float* xr = X + (size_t)row * xstride;
    const float4 v0 = ldg4(xr + lane * 4);
    const float4 v1 = ldg4(xr + 256 + lane * 4);
    const float4 v2 = ldg4(xr + 512 + lane * 4);
    float s = (v0.x + v0.y) + (v0.z + v0.w) + (v1.x + v1.y) + (v1.z + v1.w) +
              (v2.x + v2.y) + (v2.z + v2.w);
    s = wave_sum(s);
    const float mu = s * (1.f / DIM);
    float q = 0.f;
    q += (v0.x - mu) * (v0.x - mu) + (v0.y - mu) * (v0.y - mu) +
         (v0.z - mu) * (v0.z - mu) + (v0.w - mu) * (v0.w - mu);
    q += (v1.x - mu) * (v1.x - mu) + (v1.y - mu) * (v1.y - mu) +
         (v1.z - mu) * (v1.z - mu) + (v1.w - mu) * (v1.w - mu);
    q += (v2.x - mu) * (v2.x - mu) + (v2.y - mu) * (v2.y - mu) +
         (v2.z - mu) * (v2.z - mu) + (v2.w - mu) * (v2.w - mu);
    q = wave_sum(q);
    const float rr = rsqrtf(q * (1.f / DIM) + 1e-6f);
    const float4 g0 = ldg4(g + lane * 4), g1 = ldg4(g + 256 + lane * 4), g2 = ldg4(g + 512 + lane * 4);
    const float4 b0 = ldg4(be + lane * 4), b1 = ldg4(be + 256 + lane * 4), b2 = ldg4(be + 512 + lane * 4);
    float* yr = Y + (size_t)row * DIM;
    float4 o;
    o.x = (v0.x - mu) * rr * g0.x + b0.x;
    o.y = (v0.y - mu) * rr * g0.y + b0.y;
    o.z = (v0.z - mu) * rr * g0.z + b0.z;
    o.w = (v0.w - mu) * rr * g0.w + b0.w;
    *reinterpret_cast<float4*>(yr + lane * 4) = o;
    o.x = (v1.x - mu) * rr * g1.x + b1.x;
    o.y = (v1.y - mu) * rr * g1.y + b1.y;
    o.z = (v1.z - mu) * rr * g1.z + b1.z;
    o.w = (v1.w - mu) * rr * g1.w + b1.w;
    *reinterpret_cast<float4*>(yr + 256 + lane * 4) = o;
    o.x = (v2.x - mu) * rr * g2.x + b2.x;
    o.y = (v2.y - mu) * rr * g2.y + b2.y;
    o.z = (v2.z - mu) * rr * g2.z + b2.z;
    o.w = (v2.w - mu) * rr * g2.w + b2.w;
    *reinterpret_cast<float4*>(yr + 512 + lane * 4) = o;
}

// ---------------- attention: one block per (b,h) ----------------
// LDS: K (padded rows 256 for unguarded reads), V, vnorm. Pad 65 -> bank=(row+col)%32,
// 2 lanes/bank = conflict-free. Scores & PV use __shfl broadcast to halve LDS traffic.
__global__ __launch_bounds__(256, 1) void attn_k(const float* __restrict__ qkv,
    float* __restrict__ out, const int* __restrict__ mask, float* __restrict__ imp_bh)
{
    __shared__ float Ks[256][65];
    __shared__ float Vs[T][65];
    __shared__ float vn[T];
    const int bh = blockIdx.x;
    const int b = bh / NH, h = bh % NH;
    const float* base = qkv + (size_t)b * T * (3 * DIM) + h * HD;

    for (int idx = threadIdx.x; idx < T * HD; idx += 256) {
        const int r = idx >> 6, c = idx & 63;
        const float* p = base + (size_t)r * (3 * DIM) + c;
        Ks[r][c] = p[DIM];
        Vs[r][c] = p[2 * DIM];
    }
    __syncthreads();
    for (int j = threadIdx.x; j < T; j += 256) {
        float s = 0.f;
#pragma unroll 8
        for (int c = 0; c < 64; c++) { const float v = Vs[j][c]; s += v * v; }
        vn[j] = sqrtf(s);
    }
    __syncthreads();

    const int w = threadIdx.x >> 6, lane = threadIdx.x & 63;
    int mk[4];
#pragma unroll
    for (int r = 0; r < 4; r++) {
        const int j = lane + r * 64;
        mk[r] = (j < T) ? mask[j] : 0;
    }

    for (int t = w; t < T; t += 4) {
        const float qown = base[(size_t)t * (3 * DIM) + lane];
        float accs[4] = {0.f, 0.f, 0.f, 0.f};
#pragma unroll 16
        for (int c = 0; c < 64; c++) {
            const float qc = __shfl(qown, c);
            accs[0] += qc * Ks[lane][c];
            accs[1] += qc * Ks[lane + 64][c];
            accs[2] += qc * Ks[lane + 128][c];
            accs[3] += qc * Ks[lane + 192][c];
        }
        float e[4];
        float mx = -1e30f;
#pragma unroll
        for (int r = 0; r < 4; r++) {
            e[r] = mk[r] ? accs[r] * 0.125f : -1e9f;
            mx = fmaxf(mx, e[r]);
        }
        mx = wave_max(mx);
        float sum = 0.f;
#pragma unroll
        for (int r = 0; r < 4; r++) {
            const int j = lane + r * 64;
            const float ev = (j < T) ? __expf(e[r] - mx) : 0.f;
            e[r] = ev;
            sum += ev;
        }
        sum = wave_sum(sum);
        const float inv = 1.f / sum;

        float o = 0.f;
#pragma unroll
        for (int r = 0; r < 3; r++) {
#pragma unroll 16
            for (int s = 0; s < 64; s++) o += __shfl(e[r], s) * Vs[r * 64 + s][lane];
        }
#pragma unroll
        for (int s = 0; s < 5; s++) o += __shfl(e[3], s) * Vs[192 + s][lane];
        o *= inv;
        out[((size_t)b * T + t) * DIM + h * HD + lane] = o;

        if (t == 0) {
#pragma unroll
            for (int r = 0; r < 4; r++) {
                const int j = lane + r * 64;
                if (j >= 1 && j < T)
                    imp_bh[(size_t)bh * NP + (j - 1)] = e[r] * inv * vn[j];
            }
        }
    }
}

// ---------------- pruning decision (1 block) ----------------
// state[0]=prev_mass, state[1]=N (as float), state[2]=prev_valid
__global__ void prune_k(const float* __restrict__ imp_bh, int* mask, float* state)
{
    __shared__ float imp[NP];
    __shared__ int smask[NP];
    __shared__ int s_Nnext;
    const int tid = threadIdx.x;
    if (tid < NP) {
        float s = 0.f;
        for (int r = 0; r < BSZ * NH; r++) s += imp_bh[(size_t)r * NP + tid];
        const int m = mask[1 + tid];
        smask[tid] = m;
        imp[tid] = m ? (s * (1.f / (BSZ * NH))) : 0.f;
    }
    __syncthreads();
    if (tid == 0) {
        float mass = 0.f;
        for (int j = 0; j < NP; j++) mass += imp[j];
        const float Nf = state[1];
        const float prev_mass = state[0];
        const int prev_valid = (int)state[2];
        float ent = 0.f;
        for (int j = 0; j < NP; j++) {
            if (smask[j]) {
                const float p = imp[j] / (mass + 1e-6f);
                ent -= p * logf(p + 1e-6f);
            }
        }
        const float rho = ent / logf(Nf);
        float kr = 1.f - 0.01f * rho * mass / (prev_mass + 1e-6f);
        kr = fminf(fmaxf(kr, 0.f), 1.f);
        if (!prev_valid) kr = 1.f;
        int Nn = (int)floorf(Nf * kr);
        if (Nn < 16) Nn = 16;
        const int Ni = (int)Nf;
        Nn = (Ni > 16) ? ((Nn < Ni) ? Nn : Ni) : Ni;
        state[0] = mass;
        state[1] = (float)Nn;
        state[2] = (Ni > 16) ? 1.f : 0.f;
        s_Nnext = Nn;
        mask[0] = 1;
    }
    __syncthreads();
    if (tid < NP) {
        const float kj = smask[tid] ? -imp[tid] : INFINITY;
        int rank = 0;
        for (int k = 0; k < NP; k++) {
            const float kk = smask[k] ? -imp[k] : INFINITY;
            rank += (kk < kj || (kk == kj && k < tid)) ? 1 : 0;
        }
        mask[1 + tid] = (rank < s_Nnext) ? 1 : 0;
    }
}

// ---------------- state init (ws is re-poisoned before every launch) ----------------
__global__ void init_k(int* mask, float* state)
{
    const int t = threadIdx.x;
    if (t < T) mask[t] = 1;
    if (t == 0) {
        state[0] = 0.f;
        state[1] = (float)NP;
        state[2] = 0.f;
    }
}

// ---------------- launch ----------------
extern "C" void kernel_launch(void* const* d_in, const int* in_sizes, int n_in,
                              void* d_out, int out_size, void* d_ws, size_t ws_size,
                              hipStream_t stream)
{
    const float* x_img   = (const float*)d_in[0];
    const float* cls_t   = (const float*)d_in[1];
    const float* pos_e   = (const float*)d_in[2];
    const float* patch_w = (const float*)d_in[3];
    const float* patch_b = (const float*)d_in[4];
    const float* ln1_g   = (const float*)d_in[5];
    const float* ln1_b   = (const float*)d_in[6];
    const float* qkv_w   = (const float*)d_in[7];
    const float* qkv_b   = (const float*)d_in[8];
    const float* proj_w  = (const float*)d_in[9];
    const float* proj_b  = (const float*)d_in[10];
    const float* ln2_g   = (const float*)d_in[11];
    const float* ln2_b   = (const float*)d_in[12];
    const float* fc1_w   = (const float*)d_in[13];
    const float* fc1_b   = (const float*)d_in[14];
    const float* fc2_w   = (const float*)d_in[15];
    const float* fc2_b   = (const float*)d_in[16];
    const float* norm_g  = (const float*)d_in[17];
    const float* norm_b  = (const float*)d_in[18];
    const float* head_w  = (const float*)d_in[19];
    const float* head_b  = (const float*)d_in[20];
    float* out = (float*)d_out;
    float* ws  = (float*)d_ws;

    // workspace layout (floats): X | H | ATT | BIG(qkv or ff, not both live) | HC | IMP | mask | state
    const size_t SZX = (size_t)NTOK * DIM;          // 9,682,944
    float* X   = ws;
    float* Hb  = ws + SZX;
    float* ATT = ws + 2 * SZX;
    float* BIG = ws + 3 * SZX;                      // NTOK*FFD = 38,731,776 floats
    float* HC  = BIG + (size_t)NTOK * FFD;          // 64*768
    float* IMP = HC + (size_t)BSZ * DIM;            // 768*196
    int*   msk = (int*)(IMP + (size_t)BSZ * NH * NP);
    float* st  = (float*)(msk + 256);
    // total ~272 MB

    init_k<<<1, 256, 0, stream>>>(msk, st);
    clspos_k<<<(BSZ * DIM + 255) / 256, 256, 0, stream>>>(X, cls_t, pos_e);
    patch_gemm_k<<<dim3(NPATCH / BM, DIM / BN), 256, 0, stream>>>(x_img, patch_w, patch_b, pos_e, X);

    const int gm = (NTOK + BM - 1) / BM;  // 99
    for (int i = 0; i < DEPTH; i++) {
        ln_k<<<(NTOK + 3) / 4, 256, 0, stream>>>(X, ln1_g + i * DIM, ln1_b + i * DIM, Hb, NTOK, (size_t)DIM);
        gemm_k<0><<<dim3(gm, (3 * DIM) / BN), 256, 0, stream>>>(
            Hb, qkv_w + (size_t)i * DIM * 3 * DIM, qkv_b + (size_t)i * 3 * DIM, nullptr, BIG, NTOK, 3 * DIM, DIM);
        attn_k<<<BSZ * NH, 256, 0, stream>>>(BIG, ATT, msk, IMP);
        gemm_k<1><<<dim3(gm, DIM / BN), 256, 0, stream>>>(
            ATT, proj_w + (size_t)i * DIM * DIM, proj_b + (size_t)i * DIM, X, X, NTOK, DIM, DIM);
        ln_k<<<(NTOK + 3) / 4, 256, 0, stream>>>(X, ln2_g + i * DIM, ln2_b + i * DIM, Hb, NTOK, (size_t)DIM);
        gemm_k<2><<<dim3(gm, FFD / BN), 256, 0, stream>>>(
            Hb, fc1_w + (size_t)i * DIM * FFD, fc1_b + (size_t)i * FFD, nullptr, BIG, NTOK, FFD, DIM);
        gemm_k<1><<<dim3(gm, DIM / BN), 256, 0, stream>>>(
            BIG, fc2_w + (size_t)i * FFD * DIM, fc2_b + (size_t)i * DIM, X, X, NTOK, DIM, FFD);
        prune_k<<<1, 256, 0, stream>>>(IMP, msk, st);
    }

    ln_k<<<16, 256, 0, stream>>>(X, norm_g, norm_b, HC, BSZ, (size_t)T * DIM);
    gemm_k<0><<<dim3(1, (NC + BN - 1) / BN), 256, 0, stream>>>(
        HC, head_w, head_b, nullptr, out, BSZ, NC, DIM);
}

// Round 2
// 20261.754 us; speedup vs baseline: 1.9806x; 1.9806x over previous
//
#include <hip/hip_runtime.h>
#include <math.h>

// ---------------- problem constants ----------------
#define DEPTH 12
#define BSZ   64
#define T     197
#define NP    196
#define DIM   768
#define NH    12
#define HD    64
#define FFD   3072
#define NC    1000
#define NTOK  (BSZ * T)     // 12608
#define NPATCH (BSZ * NP)   // 12544

typedef __attribute__((ext_vector_type(8))) short s16x8;
typedef __attribute__((ext_vector_type(4))) float f32x4;

// ---------------- helpers ----------------
__device__ __forceinline__ float4 ldg4(const float* p) {
    return *reinterpret_cast<const float4*>(p);
}
__device__ __forceinline__ float wave_sum(float v) {
#pragma unroll
    for (int off = 32; off >= 1; off >>= 1) v += __shfl_xor(v, off);
    return v;
}
__device__ __forceinline__ float wave_max(float v) {
#pragma unroll
    for (int off = 32; off >= 1; off >>= 1) v = fmaxf(v, __shfl_xor(v, off));
    return v;
}
// fp32 -> bf16 (RNE) and back
__device__ __forceinline__ unsigned short f2bf(float x) {
    unsigned u = __float_as_uint(x);
    return (unsigned short)((u + 0x7fffu + ((u >> 16) & 1u)) >> 16);
}
__device__ __forceinline__ float bf2f(unsigned short h) {
    return __uint_as_float(((unsigned)h) << 16);
}

// async global->LDS, 16B per lane (dest must be linear: base + lane*16)
__device__ __forceinline__ void gload16(const unsigned short* g, unsigned short* l) {
#if __has_builtin(__builtin_amdgcn_global_load_lds)
    __builtin_amdgcn_global_load_lds(
        (const __attribute__((address_space(1))) unsigned int*)(const void*)g,
        (__attribute__((address_space(3))) unsigned int*)(void*)l, 16, 0, 0);
#else
    *reinterpret_cast<uint4*>(l) = *reinterpret_cast<const uint4*>(g);
#endif
}

// ======================================================================
// bf16x2-split MFMA GEMM:  C[M,N] = A @ B^T_stored  where A = Ah+Al (bf16),
// B is stored TRANSPOSED split: Bh/Bl are [N][K].  C = Ah*Bh + Ah*Bl + Al*Bh.
// 128x128 tile, BK=32, 4 waves (2x2), 16x16x32 MFMA, double-buffered LDS,
// XOR slot swizzle (slot ^= row&3) applied to staging SOURCE + frag READ.
// EPI: 0 = fp32 +bias     (qkv -> Cf, stride N)
//      1 = fp32 +bias+res (proj/fc2 -> Cf=X, res=aux)
//      2 = gelu(.) then split-bf16 -> Gh/Gl  (fc1)
//      3 = patch: row r=(b,p) -> Cf=X row b*197+1+p, +bias+pos(aux)
// ======================================================================
__device__ __forceinline__ void stage32(
    const unsigned short* __restrict__ Ah, const unsigned short* __restrict__ Al,
    const unsigned short* __restrict__ Bh, const unsigned short* __restrict__ Bl,
    unsigned short* sAh, unsigned short* sAl, unsigned short* sBh, unsigned short* sBl,
    int tid, int m0, int n0, int M, size_t K, int k0)
{
#pragma unroll
    for (int it = 0; it < 2; ++it) {
        const int t = tid + it * 256;               // 0..511
        const int row = t >> 2;                     // 0..127
        const int srcs = ((t & 3) ^ (row & 3)) << 3; // swizzled k-chunk (elements)
        const int dst = t << 3;                     // linear LDS dest (elements)
        const size_t ga = (size_t)(m0 + row) * K + (size_t)(k0 + srcs);
        const size_t gb = (size_t)(n0 + row) * K + (size_t)(k0 + srcs);
        if (m0 + row < M) {
            gload16(Ah + ga, sAh + dst);
            gload16(Al + ga, sAl + dst);
        }
        gload16(Bh + gb, sBh + dst);
        gload16(Bl + gb, sBl + dst);
    }
}

template <int EPI>
__global__ __launch_bounds__(256) void mgemm_k(
    const unsigned short* __restrict__ Ah, const unsigned short* __restrict__ Al,
    const unsigned short* __restrict__ Bh, const unsigned short* __restrict__ Bl,
    const float* __restrict__ bias, const float* __restrict__ aux,
    float* __restrict__ Cf, unsigned short* __restrict__ Gh, unsigned short* __restrict__ Gl,
    int M, int N, int K)
{
    __shared__ unsigned short sAh[2][4096];
    __shared__ unsigned short sAl[2][4096];
    __shared__ unsigned short sBh[2][4096];
    __shared__ unsigned short sBl[2][4096];

    const int tid = threadIdx.x;
    const int m0 = blockIdx.x * 128, n0 = blockIdx.y * 128;
    const int lane = tid & 63, wid = tid >> 6;
    const int wr = wid >> 1, wc = wid & 1;
    const int lr = lane & 15, kb = lane >> 4;
    const int slotoff = ((kb ^ (lane & 3)) << 3);   // swizzled read chunk

    f32x4 acc[4][4];
#pragma unroll
    for (int i = 0; i < 4; ++i)
#pragma unroll
        for (int j = 0; j < 4; ++j) acc[i][j] = (f32x4){0.f, 0.f, 0.f, 0.f};

    const int nk = K >> 5;
    stage32(Ah, Al, Bh, Bl, sAh[0], sAl[0], sBh[0], sBl[0], tid, m0, n0, M, (size_t)K, 0);
    __syncthreads();
    int cur = 0;
    for (int kt = 0; kt < nk; ++kt) {
        if (kt + 1 < nk)
            stage32(Ah, Al, Bh, Bl, sAh[cur ^ 1], sAl[cur ^ 1], sBh[cur ^ 1], sBl[cur ^ 1],
                    tid, m0, n0, M, (size_t)K, (kt + 1) << 5);
        s16x8 a_h[4], a_l[4];
#pragma unroll
        for (int mi = 0; mi < 4; ++mi) {
            const int off = (wr * 64 + mi * 16 + lr) * 32 + slotoff;
            a_h[mi] = *(const s16x8*)(const void*)&sAh[cur][off];
            a_l[mi] = *(const s16x8*)(const void*)&sAl[cur][off];
        }
#pragma unroll
        for (int ni = 0; ni < 4; ++ni) {
            const int off = (wc * 64 + ni * 16 + lr) * 32 + slotoff;
            const s16x8 b_h = *(const s16x8*)(const void*)&sBh[cur][off];
            const s16x8 b_l = *(const s16x8*)(const void*)&sBl[cur][off];
#pragma unroll
            for (int mi = 0; mi < 4; ++mi) {
                acc[mi][ni] = __builtin_amdgcn_mfma_f32_16x16x32_bf16(a_h[mi], b_h, acc[mi][ni], 0, 0, 0);
                acc[mi][ni] = __builtin_amdgcn_mfma_f32_16x16x32_bf16(a_h[mi], b_l, acc[mi][ni], 0, 0, 0);
                acc[mi][ni] = __builtin_amdgcn_mfma_f32_16x16x32_bf16(a_l[mi], b_h, acc[mi][ni], 0, 0, 0);
            }
        }
        __syncthreads();
        cur ^= 1;
    }

    // epilogue: C row = (lane>>4)*4 + r, col = lane&15 within each 16x16 frag
#pragma unroll
    for (int mi = 0; mi < 4; ++mi) {
#pragma unroll
        for (int ni = 0; ni < 4; ++ni) {
#pragma unroll
            for (int r = 0; r < 4; ++r) {
                const int row = m0 + wr * 64 + mi * 16 + kb * 4 + r;
                const int col = n0 + wc * 64 + ni * 16 + lr;
                if (row >= M) continue;
                float v = acc[mi][ni][r] + bias[col];
                if (EPI == 0) {
                    Cf[(size_t)row * N + col] = v;
                } else if (EPI == 1) {
                    Cf[(size_t)row * N + col] = v + aux[(size_t)row * N + col];
                } else if (EPI == 2) {
                    const float g = 0.5f * v * (1.f + erff(v * 0.70710678118654752f));
                    const unsigned short h = f2bf(g);
                    Gh[(size_t)row * N + col] = h;
                    Gl[(size_t)row * N + col] = f2bf(g - bf2f(h));
                } else {  // EPI == 3, patch embed
                    const int b2 = row / NP, p2 = row % NP;
                    const size_t orow = (size_t)b2 * T + 1 + p2;
                    Cf[orow * DIM + col] = v + aux[(size_t)(1 + p2) * DIM + col];
                }
            }
        }
    }
}

// ---------------- weight transpose + split: W[K][N] f32 -> WhT/WlT [N][K] bf16 ----------------
__global__ __launch_bounds__(256) void wsplit_k(const float* __restrict__ W,
    unsigned short* __restrict__ WhT, unsigned short* __restrict__ WlT, int K, int N)
{
    __shared__ float tile[32][33];
    const int k0 = blockIdx.x * 32, n0 = blockIdx.y * 32;
    const int tid = threadIdx.x;
    {
        const int kr = tid >> 3, nc = (tid & 7) * 4;
        const float4 v = ldg4(W + (size_t)(k0 + kr) * N + n0 + nc);
        tile[kr][nc] = v.x; tile[kr][nc + 1] = v.y; tile[kr][nc + 2] = v.z; tile[kr][nc + 3] = v.w;
    }
    __syncthreads();
    {
        const int nr = tid >> 3, kc = (tid & 7) * 4;
        alignas(8) unsigned short hh[4], ll[4];
#pragma unroll
        for (int j = 0; j < 4; ++j) {
            const float x = tile[kc + j][nr];
            hh[j] = f2bf(x);
            ll[j] = f2bf(x - bf2f(hh[j]));
        }
        const size_t o = (size_t)(n0 + nr) * K + k0 + kc;
        *reinterpret_cast<uint2*>(&WhT[o]) = *reinterpret_cast<const uint2*>(hh);
        *reinterpret_cast<uint2*>(&WlT[o]) = *reinterpret_cast<const uint2*>(ll);
    }
}

// ---------------- patchify + split: img -> Ph/Pl [12544][768] bf16 ----------------
__global__ __launch_bounds__(256) void psplit_k(const float* __restrict__ img,
    unsigned short* __restrict__ Ph, unsigned short* __restrict__ Pl)
{
    const int gid = blockIdx.x * 256 + threadIdx.x;
    if (gid >= NPATCH * 96) return;
    const int r = gid / 96, cc = (gid % 96) * 8;
    const int b = r / NP, p = r % NP;
    const int gy = p / 14, gx = p % 14;
    const int ch = cc >> 8, py = (cc >> 4) & 15, px = cc & 15;
    const float* s = img + (size_t)b * 150528 + (size_t)ch * 50176 +
                     (size_t)(gy * 16 + py) * 224 + gx * 16 + px;
    const float4 a = ldg4(s), c = ldg4(s + 4);
    const float vals[8] = {a.x, a.y, a.z, a.w, c.x, c.y, c.z, c.w};
    alignas(16) unsigned short hh[8], ll[8];
#pragma unroll
    for (int j = 0; j < 8; ++j) {
        hh[j] = f2bf(vals[j]);
        ll[j] = f2bf(vals[j] - bf2f(hh[j]));
    }
    const size_t o = (size_t)r * DIM + cc;
    *reinterpret_cast<uint4*>(&Ph[o]) = *reinterpret_cast<const uint4*>(hh);
    *reinterpret_cast<uint4*>(&Pl[o]) = *reinterpret_cast<const uint4*>(ll);
}

// ---------------- CLS row init ----------------
__global__ void clspos_k(float* __restrict__ X, const float* __restrict__ cls,
                         const float* __restrict__ pos)
{
    const int i = blockIdx.x * 256 + threadIdx.x;
    if (i < BSZ * DIM) {
        const int b = i / DIM, d = i % DIM;
        X[(size_t)b * T * DIM + d] = cls[d] + pos[d];
    }
}

// ---------------- LayerNorm (wave per row). SPLIT=1 -> bf16 hi/lo, SPLIT=0 -> fp32 ----------------
template <int SPLIT>
__global__ __launch_bounds__(256) void ln_k(const float* __restrict__ X,
    const float* __restrict__ g, const float* __restrict__ be,
    float* __restrict__ Yf, unsigned short* __restrict__ Yh, unsigned short* __restrict__ Yl,
    int rows, size_t xstride)
{
    const int w = threadIdx.x >> 6, lane = threadIdx.x & 63;
    const int row = (blockIdx.x << 2) + w;
    if (row >= rows) return;
    const float* xr = X + (size_t)row * xstride;
    float4 v[3];
    v[0] = ldg4(xr + lane * 4);
    v[1] = ldg4(xr + 256 + lane * 4);
    v[2] = ldg4(xr + 512 + lane * 4);
    float s = 0.f;
#pragma unroll
    for (int i = 0; i < 3; ++i) s += (v[i].x + v[i].y) + (v[i].z + v[i].w);
    s = wave_sum(s);
    const float mu = s * (1.f / DIM);
    float q = 0.f;
#pragma unroll
    for (int i = 0; i < 3; ++i) {
        q += (v[i].x - mu) * (v[i].x - mu) + (v[i].y - mu) * (v[i].y - mu) +
             (v[i].z - mu) * (v[i].z - mu) + (v[i].w - mu) * (v[i].w - mu);
    }
    q = wave_sum(q);
    const float rr = rsqrtf(q * (1.f / DIM) + 1e-6f);
#pragma unroll
    for (int i = 0; i < 3; ++i) {
        const int off = i * 256 + lane * 4;
        const float4 gg = ldg4(g + off);
        const float4 bb = ldg4(be + off);
        float o[4];
        o[0] = (v[i].x - mu) * rr * gg.x + bb.x;
        o[1] = (v[i].y - mu) * rr * gg.y + bb.y;
        o[2] = (v[i].z - mu) * rr * gg.z + bb.z;
        o[3] = (v[i].w - mu) * rr * gg.w + bb.w;
        if (SPLIT) {
            alignas(8) unsigned short hh[4], ll[4];
#pragma unroll
            for (int j = 0; j < 4; ++j) {
                hh[j] = f2bf(o[j]);
                ll[j] = f2bf(o[j] - bf2f(hh[j]));
            }
            *reinterpret_cast<uint2*>(&Yh[(size_t)row * DIM + off]) = *reinterpret_cast<const uint2*>(hh);
            *reinterpret_cast<uint2*>(&Yl[(size_t)row * DIM + off]) = *reinterpret_cast<const uint2*>(ll);
        } else {
            float4 ov = make_float4(o[0], o[1], o[2], o[3]);
            *reinterpret_cast<float4*>(&Yf[(size_t)row * DIM + off]) = ov;
        }
    }
}

// ---------------- attention: one block per (b,h), 16 waves ----------------
__global__ __launch_bounds__(1024, 1) void attn_k(const float* __restrict__ qkv,
    unsigned short* __restrict__ Oh, unsigned short* __restrict__ Ol,
    const int* __restrict__ mask, float* __restrict__ imp_bh)
{
    __shared__ float Ks[256][65];
    __shared__ float Vs[T][65];
    __shared__ float vn[T];
    const int bh = blockIdx.x;
    const int b = bh / NH, hidx = bh % NH;
    const float* base = qkv + (size_t)b * T * (3 * DIM) + hidx * HD;

    for (int idx = threadIdx.x; idx < T * HD; idx += 1024) {
        const int r = idx >> 6, c = idx & 63;
        const float* p = base + (size_t)r * (3 * DIM) + c;
        Ks[r][c] = p[DIM];
        Vs[r][c] = p[2 * DIM];
    }
    __syncthreads();
    for (int j = threadIdx.x; j < T; j += 1024) {
        float s = 0.f;
#pragma unroll 8
        for (int c = 0; c < 64; c++) { const float v = Vs[j][c]; s += v * v; }
        vn[j] = sqrtf(s);
    }
    __syncthreads();

    const int w = threadIdx.x >> 6, lane = threadIdx.x & 63;
    int mk[4];
#pragma unroll
    for (int r = 0; r < 4; r++) {
        const int j = lane + r * 64;
        mk[r] = (j < T) ? mask[j] : 0;
    }

    for (int t = w; t < T; t += 16) {
        const float qown = base[(size_t)t * (3 * DIM) + lane];
        float accs[4] = {0.f, 0.f, 0.f, 0.f};
#pragma unroll 16
        for (int c = 0; c < 64; c++) {
            const float qc = __shfl(qown, c);
            accs[0] += qc * Ks[lane][c];
            accs[1] += qc * Ks[lane + 64][c];
            accs[2] += qc * Ks[lane + 128][c];
            accs[3] += qc * Ks[lane + 192][c];
        }
        float e[4];
        float mx = -1e30f;
#pragma unroll
        for (int r = 0; r < 4; r++) {
            e[r] = mk[r] ? accs[r] * 0.125f : -1e9f;
            mx = fmaxf(mx, e[r]);
        }
        mx = wave_max(mx);
        float sum = 0.f;
#pragma unroll
        for (int r = 0; r < 4; r++) {
            const int j = lane + r * 64;
            const float ev = (j < T) ? __expf(e[r] - mx) : 0.f;
            e[r] = ev;
            sum += ev;
        }
        sum = wave_sum(sum);
        const float inv = 1.f / sum;

        float o = 0.f;
#pragma unroll
        for (int r = 0; r < 3; r++) {
#pragma unroll 16
            for (int s = 0; s < 64; s++) o += __shfl(e[r], s) * Vs[r * 64 + s][lane];
        }
#pragma unroll
        for (int s = 0; s < 5; s++) o += __shfl(e[3], s) * Vs[192 + s][lane];
        o *= inv;
        const size_t oi = ((size_t)b * T + t) * DIM + hidx * HD + lane;
        const unsigned short h = f2bf(o);
        Oh[oi] = h;
        Ol[oi] = f2bf(o - bf2f(h));

        if (t == 0) {
#pragma unroll
            for (int r = 0; r < 4; r++) {
                const int j = lane + r * 64;
                if (j >= 1 && j < T)
                    imp_bh[(size_t)bh * NP + (j - 1)] = e[r] * inv * vn[j];
            }
        }
    }
}

// ---------------- pruning decision (1 block) ----------------
__global__ void prune_k(const float* __restrict__ imp_bh, int* mask, float* state)
{
    __shared__ float imp[NP];
    __shared__ int smask[NP];
    __shared__ int s_Nnext;
    const int tid = threadIdx.x;
    if (tid < NP) {
        float s = 0.f;
        for (int r = 0; r < BSZ * NH; r++) s += imp_bh[(size_t)r * NP + tid];
        const int m = mask[1 + tid];
        smask[tid] = m;
        imp[tid] = m ? (s * (1.f / (BSZ * NH))) : 0.f;
    }
    __syncthreads();
    if (tid == 0) {
        float mass = 0.f;
        for (int j = 0; j < NP; j++) mass += imp[j];
        const float Nf = state[1];
        const float prev_mass = state[0];
        const int prev_valid = (int)state[2];
        float ent = 0.f;
        for (int j = 0; j < NP; j++) {
            if (smask[j]) {
                const float p = imp[j] / (mass + 1e-6f);
                ent -= p * logf(p + 1e-6f);
            }
        }
        const float rho = ent / logf(Nf);
        float kr = 1.f - 0.01f * rho * mass / (prev_mass + 1e-6f);
        kr = fminf(fmaxf(kr, 0.f), 1.f);
        if (!prev_valid) kr = 1.f;
        int Nn = (int)floorf(Nf * kr);
        if (Nn < 16) Nn = 16;
        const int Ni = (int)Nf;
        Nn = (Ni > 16) ? ((Nn < Ni) ? Nn : Ni) : Ni;
        state[0] = mass;
        state[1] = (float)Nn;
        state[2] = (Ni > 16) ? 1.f : 0.f;
        s_Nnext = Nn;
        mask[0] = 1;
    }
    __syncthreads();
    if (tid < NP) {
        const float kj = smask[tid] ? -imp[tid] : INFINITY;
        int rank = 0;
        for (int k = 0; k < NP; k++) {
            const float kk = smask[k] ? -imp[k] : INFINITY;
            rank += (kk < kj || (kk == kj && k < tid)) ? 1 : 0;
        }
        mask[1 + tid] = (rank < s_Nnext) ? 1 : 0;
    }
}

// ---------------- state init ----------------
__global__ void init_k(int* mask, float* state)
{
    const int t = threadIdx.x;
    if (t < T) mask[t] = 1;
    if (t == 0) {
        state[0] = 0.f;
        state[1] = (float)NP;
        state[2] = 0.f;
    }
}

// ---------------- fp32 GEMM for the tiny head (64x1000x768) ----------------
#define BM 128
#define BN 128
#define BK 8
__device__ __forceinline__ float4 load_b_guard(const float* wp, int ncol0, int N) {
    float4 r;
    r.x = (ncol0 + 0 < N) ? wp[0] : 0.f;
    r.y = (ncol0 + 1 < N) ? wp[1] : 0.f;
    r.z = (ncol0 + 2 < N) ? wp[2] : 0.f;
    r.w = (ncol0 + 3 < N) ? wp[3] : 0.f;
    return r;
}
__global__ __launch_bounds__(256, 2) void gemm_f32_k(
    const float* __restrict__ A, const float* __restrict__ W,
    const float* __restrict__ bias, float* C, int M, int N, int K)
{
    __shared__ float As[BK][BM];
    __shared__ float Bs[BK][BN];
    const int tid = threadIdx.x;
    const int m0 = blockIdx.x * BM, n0 = blockIdx.y * BN;
    const int tx = tid & 15, ty = tid >> 4;
    const int arow = tid >> 1, ak = (tid & 1) * 4;
    const int brow = tid >> 5, bcol = (tid & 31) * 4;
    const bool aval = (m0 + arow) < M;
    const float* Ap = A + (size_t)(m0 + arow) * K + ak;
    const float* Wp = W + (size_t)brow * N + n0 + bcol;
    const bool bfull = (n0 + BN) <= N;

    float acc[8][8];
#pragma unroll
    for (int i = 0; i < 8; i++)
#pragma unroll
        for (int j = 0; j < 8; j++) acc[i][j] = 0.f;

    float4 ar = aval ? ldg4(Ap) : make_float4(0.f, 0.f, 0.f, 0.f);
    float4 br = bfull ? ldg4(Wp) : load_b_guard(Wp, n0 + bcol, N);

    int k0 = 0;
    while (true) {
        __syncthreads();
        As[ak + 0][arow] = ar.x;
        As[ak + 1][arow] = ar.y;
        As[ak + 2][arow] = ar.z;
        As[ak + 3][arow] = ar.w;
        *reinterpret_cast<float4*>(&Bs[brow][bcol]) = br;
        __syncthreads();
        const int kn = k0 + BK;
        const bool more = kn < K;
        if (more) {
            ar = aval ? ldg4(Ap + kn) : make_float4(0.f, 0.f, 0.f, 0.f);
            const float* wp = Wp + (size_t)kn * N;
            br = bfull ? ldg4(wp) : load_b_guard(wp, n0 + bcol, N);
        }
#pragma unroll
        for (int kk = 0; kk < BK; kk++) {
            float a[8], b[8];
            *reinterpret_cast<float4*>(&a[0]) = *reinterpret_cast<const float4*>(&As[kk][ty * 4]);
            *reinterpret_cast<float4*>(&a[4]) = *reinterpret_cast<const float4*>(&As[kk][64 + ty * 4]);
            *reinterpret_cast<float4*>(&b[0]) = *reinterpret_cast<const float4*>(&Bs[kk][tx * 4]);
            *reinterpret_cast<float4*>(&b[4]) = *reinterpret_cast<const float4*>(&Bs[kk][64 + tx * 4]);
#pragma unroll
            for (int i = 0; i < 8; i++)
#pragma unroll
                for (int j = 0; j < 8; j++) acc[i][j] += a[i] * b[j];
        }
        if (!more) break;
        k0 = kn;
    }
#pragma unroll
    for (int i = 0; i < 8; i++) {
        const int m = m0 + (i < 4 ? ty * 4 + i : 64 + ty * 4 + (i - 4));
        if (m >= M) continue;
#pragma unroll
        for (int j = 0; j < 8; j++) {
            const int n = n0 + (j < 4 ? tx * 4 + j : 64 + tx * 4 + (j - 4));
            if (n >= N) continue;
            C[(size_t)m * N + n] = acc[i][j] + bias[n];
        }
    }
}

// ---------------- launch ----------------
extern "C" void kernel_launch(void* const* d_in, const int* in_sizes, int n_in,
                              void* d_out, int out_size, void* d_ws, size_t ws_size,
                              hipStream_t stream)
{
    const float* x_img   = (const float*)d_in[0];
    const float* cls_t   = (const float*)d_in[1];
    const float* pos_e   = (const float*)d_in[2];
    const float* patch_w = (const float*)d_in[3];
    const float* patch_b = (const float*)d_in[4];
    const float* ln1_g   = (const float*)d_in[5];
    const float* ln1_b   = (const float*)d_in[6];
    const float* qkv_w   = (const float*)d_in[7];
    const float* qkv_b   = (const float*)d_in[8];
    const float* proj_w  = (const float*)d_in[9];
    const float* proj_b  = (const float*)d_in[10];
    const float* ln2_g   = (const float*)d_in[11];
    const float* ln2_b   = (const float*)d_in[12];
    const float* fc1_w   = (const float*)d_in[13];
    const float* fc1_b   = (const float*)d_in[14];
    const float* fc2_w   = (const float*)d_in[15];
    const float* fc2_b   = (const float*)d_in[16];
    const float* norm_g  = (const float*)d_in[17];
    const float* norm_b  = (const float*)d_in[18];
    const float* head_w  = (const float*)d_in[19];
    const float* head_b  = (const float*)d_in[20];
    float* out = (float*)d_out;

    // ---- workspace layout (~243 MB) ----
    const size_t SZX = (size_t)NTOK * DIM;          // 9,682,944 elements
    float* X = (float*)d_ws;
    unsigned short* Hh = (unsigned short*)(X + SZX);
    unsigned short* Hl = Hh + SZX;
    float* BIG = (float*)(Hl + SZX);                // NTOK*FFD f32 bytes (155 MB)
    unsigned short* Wh = (unsigned short*)(BIG + (size_t)NTOK * FFD);
    unsigned short* Wl = Wh + (size_t)FFD * DIM;    // max weight = 3072*768
    float* HC  = (float*)(Wl + (size_t)FFD * DIM);
    float* IMP = HC + (size_t)BSZ * DIM;
    int*   msk = (int*)(IMP + (size_t)BSZ * NH * NP);
    float* st  = (float*)(msk + 256);

    // BIG overlays (never simultaneously live):
    float* QKV = BIG;                                // [NTOK][2304] f32
    unsigned short* Gh = (unsigned short*)BIG;       // [NTOK][3072] bf16 hi
    unsigned short* Gl = Gh + (size_t)NTOK * FFD;    // lo
    unsigned short* Ph = (unsigned short*)BIG;       // patch split [12544][768]
    unsigned short* Pl = Ph + (size_t)NPATCH * DIM;

    init_k<<<1, 256, 0, stream>>>(msk, st);
    clspos_k<<<(BSZ * DIM + 255) / 256, 256, 0, stream>>>(X, cls_t, pos_e);

    // patch embed: patchify+split, weight split, MFMA GEMM
    psplit_k<<<(NPATCH * 96 + 255) / 256, 256, 0, stream>>>(x_img, Ph, Pl);
    wsplit_k<<<dim3(DIM / 32, DIM / 32), 256, 0, stream>>>(patch_w, Wh, Wl, DIM, DIM);
    mgemm_k<3><<<dim3(NPATCH / 128, DIM / 128), 256, 0, stream>>>(
        Ph, Pl, Wh, Wl, patch_b, pos_e, X, nullptr, nullptr, NPATCH, DIM, DIM);

    const int gm = (NTOK + 127) / 128;  // 99
    for (int i = 0; i < DEPTH; i++) {
        ln_k<1><<<(NTOK + 3) / 4, 256, 0, stream>>>(X, ln1_g + i * DIM, ln1_b + i * DIM,
                                                    nullptr, Hh, Hl, NTOK, (size_t)DIM);
        wsplit_k<<<dim3(DIM / 32, (3 * DIM) / 32), 256, 0, stream>>>(
            qkv_w + (size_t)i * DIM * 3 * DIM, Wh, Wl, DIM, 3 * DIM);
        mgemm_k<0><<<dim3(gm, (3 * DIM) / 128), 256, 0, stream>>>(
            Hh, Hl, Wh, Wl, qkv_b + (size_t)i * 3 * DIM, nullptr, QKV, nullptr, nullptr,
            NTOK, 3 * DIM, DIM);
        attn_k<<<BSZ * NH, 1024, 0, stream>>>(QKV, Hh, Hl, msk, IMP);
        wsplit_k<<<dim3(DIM / 32, DIM / 32), 256, 0, stream>>>(
            proj_w + (size_t)i * DIM * DIM, Wh, Wl, DIM, DIM);
        mgemm_k<1><<<dim3(gm, DIM / 128), 256, 0, stream>>>(
            Hh, Hl, Wh, Wl, proj_b + (size_t)i * DIM, X, X, nullptr, nullptr,
            NTOK, DIM, DIM);
        ln_k<1><<<(NTOK + 3) / 4, 256, 0, stream>>>(X, ln2_g + i * DIM, ln2_b + i * DIM,
                                                    nullptr, Hh, Hl, NTOK, (size_t)DIM);
        wsplit_k<<<dim3(DIM / 32, FFD / 32), 256, 0, stream>>>(
            fc1_w + (size_t)i * DIM * FFD, Wh, Wl, DIM, FFD);
        mgemm_k<2><<<dim3(gm, FFD / 128), 256, 0, stream>>>(
            Hh, Hl, Wh, Wl, fc1_b + (size_t)i * FFD, nullptr, nullptr, Gh, Gl,
            NTOK, FFD, DIM);
        wsplit_k<<<dim3(FFD / 32, DIM / 32), 256, 0, stream>>>(
            fc2_w + (size_t)i * FFD * DIM, Wh, Wl, FFD, DIM);
        mgemm_k<1><<<dim3(gm, DIM / 128), 256, 0, stream>>>(
            Gh, Gl, Wh, Wl, fc2_b + (size_t)i * DIM, X, X, nullptr, nullptr,
            NTOK, DIM, FFD);
        prune_k<<<1, 256, 0, stream>>>(IMP, msk, st);
    }

    ln_k<0><<<16, 256, 0, stream>>>(X, norm_g, norm_b, HC, nullptr, nullptr,
                                    BSZ, (size_t)T * DIM);
    gemm_f32_k<<<dim3(1, (NC + 127) / 128), 256, 0, stream>>>(
        HC, head_w, head_b, out, BSZ, NC, DIM);
}

// Round 3
// 15914.171 us; speedup vs baseline: 2.5217x; 1.2732x over previous
//
#include <hip/hip_runtime.h>
#include <math.h>

// ---------------- problem constants ----------------
#define DEPTH 12
#define BSZ   64
#define T     197
#define NP    196
#define DIM   768
#define NH    12
#define HD    64
#define FFD   3072
#define NC    1000
#define NTOK  (BSZ * T)     // 12608
#define NPATCH (BSZ * NP)   // 12544
#define QROWS 208           // padded token rows for Q/K/V split buffers
#define VSTR  232           // sVt row stride (elems), 464B = 29*16 -> b128-aligned

typedef __attribute__((ext_vector_type(8))) short s16x8;
typedef __attribute__((ext_vector_type(4))) float f32x4;

// ---------------- helpers ----------------
__device__ __forceinline__ float4 ldg4(const float* p) {
    return *reinterpret_cast<const float4*>(p);
}
__device__ __forceinline__ float wave_sum(float v) {
#pragma unroll
    for (int off = 32; off >= 1; off >>= 1) v += __shfl_xor(v, off);
    return v;
}
// fp32 -> bf16 (RNE) and back
__device__ __forceinline__ unsigned short f2bf(float x) {
    unsigned u = __float_as_uint(x);
    return (unsigned short)((u + 0x7fffu + ((u >> 16) & 1u)) >> 16);
}
__device__ __forceinline__ float bf2f(unsigned short h) {
    return __uint_as_float(((unsigned)h) << 16);
}

// async global->LDS, 16B per lane (dest must be linear: base + lane*16)
__device__ __forceinline__ void gload16(const unsigned short* g, unsigned short* l) {
#if __has_builtin(__builtin_amdgcn_global_load_lds)
    __builtin_amdgcn_global_load_lds(
        (const __attribute__((address_space(1))) unsigned int*)(const void*)g,
        (__attribute__((address_space(3))) unsigned int*)(void*)l, 16, 0, 0);
#else
    *reinterpret_cast<uint4*>(l) = *reinterpret_cast<const uint4*>(g);
#endif
}

// ======================================================================
// bf16x2-split MFMA GEMM:  C[M,N] = A @ B^T_stored  where A = Ah+Al (bf16),
// B stored transposed split: Bh/Bl are [N][K].  C = Ah*Bh + Ah*Bl + Al*Bh.
// 128x128 tile, BK=32, 4 waves (2x2), 16x16x32 MFMA, double-buffered LDS.
// EPI: 1 = fp32 +bias+res (proj/fc2 -> Cf=X, res=aux)
//      2 = gelu(.) then split-bf16 -> o1h/o1l  (fc1)
//      3 = patch: row r=(b,p) -> Cf=X row b*197+1+p, +bias+pos(aux)
//      4 = qkv: split-bf16 head-major Q/K/V (o1=Q, o2=K, o3=V), [bh][208][64]
// ======================================================================
__device__ __forceinline__ void stage32(
    const unsigned short* __restrict__ Ah, const unsigned short* __restrict__ Al,
    const unsigned short* __restrict__ Bh, const unsigned short* __restrict__ Bl,
    unsigned short* sAh, unsigned short* sAl, unsigned short* sBh, unsigned short* sBl,
    int tid, int m0, int n0, int M, size_t K, int k0)
{
#pragma unroll
    for (int it = 0; it < 2; ++it) {
        const int t = tid + it * 256;               // 0..511
        const int row = t >> 2;                     // 0..127
        const int srcs = ((t & 3) ^ (row & 3)) << 3; // swizzled k-chunk (elements)
        const int dst = t << 3;                     // linear LDS dest (elements)
        const size_t ga = (size_t)(m0 + row) * K + (size_t)(k0 + srcs);
        const size_t gb = (size_t)(n0 + row) * K + (size_t)(k0 + srcs);
        if (m0 + row < M) {
            gload16(Ah + ga, sAh + dst);
            gload16(Al + ga, sAl + dst);
        }
        gload16(Bh + gb, sBh + dst);
        gload16(Bl + gb, sBl + dst);
    }
}

template <int EPI>
__global__ __launch_bounds__(256) void mgemm_k(
    const unsigned short* __restrict__ Ah, const unsigned short* __restrict__ Al,
    const unsigned short* __restrict__ Bh, const unsigned short* __restrict__ Bl,
    const float* __restrict__ bias, const float* __restrict__ aux,
    float* __restrict__ Cf,
    unsigned short* __restrict__ o1h, unsigned short* __restrict__ o1l,
    unsigned short* __restrict__ o2h, unsigned short* __restrict__ o2l,
    unsigned short* __restrict__ o3h, unsigned short* __restrict__ o3l,
    int M, int N, int K)
{
    __shared__ unsigned short sAh[2][4096];
    __shared__ unsigned short sAl[2][4096];
    __shared__ unsigned short sBh[2][4096];
    __shared__ unsigned short sBl[2][4096];

    const int tid = threadIdx.x;
    const int m0 = blockIdx.x * 128, n0 = blockIdx.y * 128;
    const int lane = tid & 63, wid = tid >> 6;
    const int wr = wid >> 1, wc = wid & 1;
    const int lr = lane & 15, kb = lane >> 4;
    const int slotoff = ((kb ^ (lane & 3)) << 3);   // swizzled read chunk

    f32x4 acc[4][4];
#pragma unroll
    for (int i = 0; i < 4; ++i)
#pragma unroll
        for (int j = 0; j < 4; ++j) acc[i][j] = (f32x4){0.f, 0.f, 0.f, 0.f};

    const int nk = K >> 5;
    stage32(Ah, Al, Bh, Bl, sAh[0], sAl[0], sBh[0], sBl[0], tid, m0, n0, M, (size_t)K, 0);
    __syncthreads();
    int cur = 0;
    for (int kt = 0; kt < nk; ++kt) {
        if (kt + 1 < nk)
            stage32(Ah, Al, Bh, Bl, sAh[cur ^ 1], sAl[cur ^ 1], sBh[cur ^ 1], sBl[cur ^ 1],
                    tid, m0, n0, M, (size_t)K, (kt + 1) << 5);
        s16x8 a_h[4], a_l[4];
#pragma unroll
        for (int mi = 0; mi < 4; ++mi) {
            const int off = (wr * 64 + mi * 16 + lr) * 32 + slotoff;
            a_h[mi] = *(const s16x8*)(const void*)&sAh[cur][off];
            a_l[mi] = *(const s16x8*)(const void*)&sAl[cur][off];
        }
#pragma unroll
        for (int ni = 0; ni < 4; ++ni) {
            const int off = (wc * 64 + ni * 16 + lr) * 32 + slotoff;
            const s16x8 b_h = *(const s16x8*)(const void*)&sBh[cur][off];
            const s16x8 b_l = *(const s16x8*)(const void*)&sBl[cur][off];
#pragma unroll
            for (int mi = 0; mi < 4; ++mi) {
                acc[mi][ni] = __builtin_amdgcn_mfma_f32_16x16x32_bf16(a_h[mi], b_h, acc[mi][ni], 0, 0, 0);
                acc[mi][ni] = __builtin_amdgcn_mfma_f32_16x16x32_bf16(a_h[mi], b_l, acc[mi][ni], 0, 0, 0);
                acc[mi][ni] = __builtin_amdgcn_mfma_f32_16x16x32_bf16(a_l[mi], b_h, acc[mi][ni], 0, 0, 0);
            }
        }
        __syncthreads();
        cur ^= 1;
    }

    // epilogue: C row = kb*4 + r (+16*mi +64*wr), col = lr (+16*ni +64*wc)
#pragma unroll
    for (int mi = 0; mi < 4; ++mi) {
#pragma unroll
        for (int ni = 0; ni < 4; ++ni) {
#pragma unroll
            for (int r = 0; r < 4; ++r) {
                const int row = m0 + wr * 64 + mi * 16 + kb * 4 + r;
                const int col = n0 + wc * 64 + ni * 16 + lr;
                if (row >= M) continue;
                float v = acc[mi][ni][r] + bias[col];
                if (EPI == 1) {
                    Cf[(size_t)row * N + col] = v + aux[(size_t)row * N + col];
                } else if (EPI == 2) {
                    const float g = 0.5f * v * (1.f + erff(v * 0.70710678118654752f));
                    const unsigned short h = f2bf(g);
                    o1h[(size_t)row * N + col] = h;
                    o1l[(size_t)row * N + col] = f2bf(g - bf2f(h));
                } else if (EPI == 3) {  // patch embed
                    const int b2 = row / NP, p2 = row % NP;
                    const size_t orow = (size_t)b2 * T + 1 + p2;
                    Cf[orow * DIM + col] = v + aux[(size_t)(1 + p2) * DIM + col];
                } else {  // EPI == 4: qkv split head-major
                    const int sec = col / 768;          // 0=Q 1=K 2=V
                    const int h8 = (col % 768) >> 6;    // head
                    const int dd = col & 63;
                    const int bb = row / T, tt = row % T;
                    unsigned short* dh = (sec == 0) ? o1h : (sec == 1) ? o2h : o3h;
                    unsigned short* dl = (sec == 0) ? o1l : (sec == 1) ? o2l : o3l;
                    const size_t adr = ((size_t)(bb * NH + h8)) * (QROWS * 64) + (size_t)tt * 64 + dd;
                    const unsigned short hv = f2bf(v);
                    dh[adr] = hv;
                    dl[adr] = f2bf(v - bf2f(hv));
                }
            }
        }
    }
}

// ---------------- weight transpose + split: W[K][N] f32 -> WhT/WlT [N][K] bf16 ----------------
__global__ __launch_bounds__(256) void wsplit_k(const float* __restrict__ W,
    unsigned short* __restrict__ WhT, unsigned short* __restrict__ WlT, int K, int N)
{
    __shared__ float tile[32][33];
    const int k0 = blockIdx.x * 32, n0 = blockIdx.y * 32;
    const int tid = threadIdx.x;
    {
        const int kr = tid >> 3, nc = (tid & 7) * 4;
        const float4 v = ldg4(W + (size_t)(k0 + kr) * N + n0 + nc);
        tile[kr][nc] = v.x; tile[kr][nc + 1] = v.y; tile[kr][nc + 2] = v.z; tile[kr][nc + 3] = v.w;
    }
    __syncthreads();
    {
        const int nr = tid >> 3, kc = (tid & 7) * 4;
        alignas(8) unsigned short hh[4], ll[4];
#pragma unroll
        for (int j = 0; j < 4; ++j) {
            const float x = tile[kc + j][nr];
            hh[j] = f2bf(x);
            ll[j] = f2bf(x - bf2f(hh[j]));
        }
        const size_t o = (size_t)(n0 + nr) * K + k0 + kc;
        *reinterpret_cast<uint2*>(&WhT[o]) = *reinterpret_cast<const uint2*>(hh);
        *reinterpret_cast<uint2*>(&WlT[o]) = *reinterpret_cast<const uint2*>(ll);
    }
}

// ---------------- patchify + split: img -> Ph/Pl [12544][768] bf16 ----------------
__global__ __launch_bounds__(256) void psplit_k(const float* __restrict__ img,
    unsigned short* __restrict__ Ph, unsigned short* __restrict__ Pl)
{
    const int gid = blockIdx.x * 256 + threadIdx.x;
    if (gid >= NPATCH * 96) return;
    const int r = gid / 96, cc = (gid % 96) * 8;
    const int b = r / NP, p = r % NP;
    const int gy = p / 14, gx = p % 14;
    const int ch = cc >> 8, py = (cc >> 4) & 15, px = cc & 15;
    const float* s = img + (size_t)b * 150528 + (size_t)ch * 50176 +
                     (size_t)(gy * 16 + py) * 224 + gx * 16 + px;
    const float4 a = ldg4(s), c = ldg4(s + 4);
    const float vals[8] = {a.x, a.y, a.z, a.w, c.x, c.y, c.z, c.w};
    alignas(16) unsigned short hh[8], ll[8];
#pragma unroll
    for (int j = 0; j < 8; ++j) {
        hh[j] = f2bf(vals[j]);
        ll[j] = f2bf(vals[j] - bf2f(hh[j]));
    }
    const size_t o = (size_t)r * DIM + cc;
    *reinterpret_cast<uint4*>(&Ph[o]) = *reinterpret_cast<const uint4*>(hh);
    *reinterpret_cast<uint4*>(&Pl[o]) = *reinterpret_cast<const uint4*>(ll);
}

// ---------------- CLS row init ----------------
__global__ void clspos_k(float* __restrict__ X, const float* __restrict__ cls,
                         const float* __restrict__ pos)
{
    const int i = blockIdx.x * 256 + threadIdx.x;
    if (i < BSZ * DIM) {
        const int b = i / DIM, d = i % DIM;
        X[(size_t)b * T * DIM + d] = cls[d] + pos[d];
    }
}

// ---------------- LayerNorm (wave per row). SPLIT=1 -> bf16 hi/lo, SPLIT=0 -> fp32 ----------------
template <int SPLIT>
__global__ __launch_bounds__(256) void ln_k(const float* __restrict__ X,
    const float* __restrict__ g, const float* __restrict__ be,
    float* __restrict__ Yf, unsigned short* __restrict__ Yh, unsigned short* __restrict__ Yl,
    int rows, size_t xstride)
{
    const int w = threadIdx.x >> 6, lane = threadIdx.x & 63;
    const int row = (blockIdx.x << 2) + w;
    if (row >= rows) return;
    const float* xr = X + (size_t)row * xstride;
    float4 v[3];
    v[0] = ldg4(xr + lane * 4);
    v[1] = ldg4(xr + 256 + lane * 4);
    v[2] = ldg4(xr + 512 + lane * 4);
    float s = 0.f;
#pragma unroll
    for (int i = 0; i < 3; ++i) s += (v[i].x + v[i].y) + (v[i].z + v[i].w);
    s = wave_sum(s);
    const float mu = s * (1.f / DIM);
    float q = 0.f;
#pragma unroll
    for (int i = 0; i < 3; ++i) {
        q += (v[i].x - mu) * (v[i].x - mu) + (v[i].y - mu) * (v[i].y - mu) +
             (v[i].z - mu) * (v[i].z - mu) + (v[i].w - mu) * (v[i].w - mu);
    }
    q = wave_sum(q);
    const float rr = rsqrtf(q * (1.f / DIM) + 1e-6f);
#pragma unroll
    for (int i = 0; i < 3; ++i) {
        const int off = i * 256 + lane * 4;
        const float4 gg = ldg4(g + off);
        const float4 bb = ldg4(be + off);
        float o[4];
        o[0] = (v[i].x - mu) * rr * gg.x + bb.x;
        o[1] = (v[i].y - mu) * rr * gg.y + bb.y;
        o[2] = (v[i].z - mu) * rr * gg.z + bb.z;
        o[3] = (v[i].w - mu) * rr * gg.w + bb.w;
        if (SPLIT) {
            alignas(8) unsigned short hh[4], ll[4];
#pragma unroll
            for (int j = 0; j < 4; ++j) {
                hh[j] = f2bf(o[j]);
                ll[j] = f2bf(o[j] - bf2f(hh[j]));
            }
            *reinterpret_cast<uint2*>(&Yh[(size_t)row * DIM + off]) = *reinterpret_cast<const uint2*>(hh);
            *reinterpret_cast<uint2*>(&Yl[(size_t)row * DIM + off]) = *reinterpret_cast<const uint2*>(ll);
        } else {
            float4 ov = make_float4(o[0], o[1], o[2], o[3]);
            *reinterpret_cast<float4*>(&Yf[(size_t)row * DIM + off]) = ov;
        }
    }
}

// ======================================================================
// MFMA attention: block = (b,h), 8 waves. Split-bf16 3-term products.
// S^T = mfma(K, Q)  -> lane holds P-row for q = lane&15 (52 j-vals)
// softmax: per-lane + shfl_xor(16,32) across the 4 kb-lanes
// O = mfma(P, Vt)   -> P A-frags built via 16 shfl per k-step
// ======================================================================
__global__ __launch_bounds__(512, 1) void attn_k(
    const unsigned short* __restrict__ Qh_g, const unsigned short* __restrict__ Ql_g,
    const unsigned short* __restrict__ Kh_g, const unsigned short* __restrict__ Kl_g,
    const unsigned short* __restrict__ Vh_g, const unsigned short* __restrict__ Vl_g,
    unsigned short* __restrict__ Oh, unsigned short* __restrict__ Ol,
    const int* __restrict__ mask, float* __restrict__ imp_bh)
{
    __shared__ unsigned short sKh[QROWS * 64];
    __shared__ unsigned short sKl[QROWS * 64];
    __shared__ unsigned short sVth[64 * VSTR];
    __shared__ unsigned short sVtl[64 * VSTR];
    __shared__ float svn[224];
    __shared__ int smask[224];

    const int bh = blockIdx.x;
    const int b = bh / NH, h = bh % NH;
    const int tid = threadIdx.x, lane = tid & 63, wv = tid >> 6;
    const int lr = lane & 15, kb = lane >> 4;
    const size_t base = (size_t)bh * (QROWS * 64);

    // stage K hi/lo via global_load_lds, slot-XOR swizzle (src-swizzled, dest linear)
    for (int c = tid; c < (QROWS * 64 / 8); c += 512) {
        const int row = c >> 3, s = c & 7;
        const int srce = row * 64 + ((s ^ (row & 7)) << 3);
        gload16(Kh_g + base + srce, sKh + (c << 3));
        gload16(Kl_g + base + srce, sKl + (c << 3));
    }
    // V: global [208][64] -> transposed LDS [64][VSTR]
    for (int t = wv; t < QROWS; t += 8) {
        const unsigned short vh = Vh_g[base + t * 64 + lane];
        const unsigned short vl = Vl_g[base + t * 64 + lane];
        sVth[lane * VSTR + t] = vh;
        sVtl[lane * VSTR + t] = vl;
    }
    if (tid < 224) smask[tid] = (tid < T) ? mask[tid] : 0;
    __syncthreads();
    // vnorm (fp32 from split halves)
    for (int j = tid; j < 224; j += 512) {
        float s = 0.f;
        for (int d = 0; d < 64; ++d) {
            const float v = bf2f(sVth[d * VSTR + j]) + bf2f(sVtl[d * VSTR + j]);
            s += v * v;
        }
        svn[j] = sqrtf(s);
    }
    __syncthreads();

    // hoisted per-lane key mask bits: bit nf*4+r -> j = nf*16 + kb*4 + r
    unsigned long long mk = 0ull;
#pragma unroll
    for (int nf = 0; nf < 13; ++nf)
#pragma unroll
        for (int r = 0; r < 4; ++r)
            if (smask[nf * 16 + kb * 4 + r]) mk |= (1ull << (nf * 4 + r));

    for (int qf = wv; qf < 13; qf += 8) {
        const int q0 = qf * 16;
        // Q B-frags (q = lr)
        s16x8 qh[2], ql[2];
#pragma unroll
        for (int ks = 0; ks < 2; ++ks) {
            const size_t qa = base + (size_t)(q0 + lr) * 64 + ks * 32 + kb * 8;
            qh[ks] = *(const s16x8*)(const void*)(Qh_g + qa);
            ql[ks] = *(const s16x8*)(const void*)(Ql_g + qa);
        }
        // S^T: C[j][q], lane: q=lr, j = nf*16 + kb*4 + r
        f32x4 p[13];
#pragma unroll
        for (int nf = 0; nf < 13; ++nf) {
            f32x4 acc = (f32x4){0.f, 0.f, 0.f, 0.f};
#pragma unroll
            for (int ks = 0; ks < 2; ++ks) {
                const int row = nf * 16 + lr;
                const int off = row * 64 + (((ks * 4 + kb) ^ (row & 7)) << 3);
                const s16x8 kh = *(const s16x8*)(const void*)(sKh + off);
                const s16x8 kl = *(const s16x8*)(const void*)(sKl + off);
                acc = __builtin_amdgcn_mfma_f32_16x16x32_bf16(kh, qh[ks], acc, 0, 0, 0);
                acc = __builtin_amdgcn_mfma_f32_16x16x32_bf16(kl, qh[ks], acc, 0, 0, 0);
                acc = __builtin_amdgcn_mfma_f32_16x16x32_bf16(kh, ql[ks], acc, 0, 0, 0);
            }
            p[nf] = acc;
        }
        // masked scale + softmax (row q = lr spread over 4 kb-lanes)
        float mx = -1e30f;
#pragma unroll
        for (int nf = 0; nf < 13; ++nf)
#pragma unroll
            for (int r = 0; r < 4; ++r) {
                const float v = ((mk >> (nf * 4 + r)) & 1ull) ? p[nf][r] * 0.125f : -1e9f;
                p[nf][r] = v;
                mx = fmaxf(mx, v);
            }
        mx = fmaxf(mx, __shfl_xor(mx, 16));
        mx = fmaxf(mx, __shfl_xor(mx, 32));
        float sum = 0.f;
#pragma unroll
        for (int nf = 0; nf < 13; ++nf)
#pragma unroll
            for (int r = 0; r < 4; ++r) {
                const float e = __expf(p[nf][r] - mx);
                p[nf][r] = e;
                sum += e;
            }
        sum += __shfl_xor(sum, 16);
        sum += __shfl_xor(sum, 32);
        const float inv = 1.f / sum;
#pragma unroll
        for (int nf = 0; nf < 13; ++nf)
#pragma unroll
            for (int r = 0; r < 4; ++r) p[nf][r] *= inv;

        // CLS importance (q==0 lives on lanes lr==0, wave of qf==0)
        if (qf == 0 && lr == 0) {
#pragma unroll
            for (int nf = 0; nf < 13; ++nf)
#pragma unroll
                for (int r = 0; r < 4; ++r) {
                    const int j = nf * 16 + kb * 4 + r;
                    if (j >= 1 && j < T)
                        imp_bh[(size_t)bh * NP + (j - 1)] = p[nf][r] * svn[j];
                }
        }

        // PV: O = mfma(P, Vt);  A-frag: P[q=lr][j = ks*32 + kb*8 + jj]
        f32x4 o[4];
#pragma unroll
        for (int mi = 0; mi < 4; ++mi) o[mi] = (f32x4){0.f, 0.f, 0.f, 0.f};
#pragma unroll
        for (int ks = 0; ks < 7; ++ks) {
            s16x8 pa_h, pa_l;
#pragma unroll
            for (int jj = 0; jj < 8; ++jj) {
                const int srcl = lr + 16 * (2 * (kb & 1) + (jj >> 2));
                const float vA = __shfl(p[2 * ks][jj & 3], srcl);
                const float vB = (2 * ks + 1 < 13) ? __shfl(p[2 * ks + 1][jj & 3], srcl) : 0.f;
                float v = (kb >> 1) ? vB : vA;
                const unsigned short hh = f2bf(v);
                pa_h[jj] = (short)hh;
                pa_l[jj] = (short)f2bf(v - bf2f(hh));
            }
#pragma unroll
            for (int mi = 0; mi < 4; ++mi) {
                const int off = (mi * 16 + lr) * VSTR + ks * 32 + kb * 8;
                const s16x8 vh = *(const s16x8*)(const void*)(sVth + off);
                const s16x8 vl = *(const s16x8*)(const void*)(sVtl + off);
                o[mi] = __builtin_amdgcn_mfma_f32_16x16x32_bf16(pa_h, vh, o[mi], 0, 0, 0);
                o[mi] = __builtin_amdgcn_mfma_f32_16x16x32_bf16(pa_l, vh, o[mi], 0, 0, 0);
                o[mi] = __builtin_amdgcn_mfma_f32_16x16x32_bf16(pa_h, vl, o[mi], 0, 0, 0);
            }
        }
        // write O: row q = kb*4+r, col d = mi*16+lr  (split bf16 into Oh/Ol)
#pragma unroll
        for (int mi = 0; mi < 4; ++mi)
#pragma unroll
            for (int r = 0; r < 4; ++r) {
                const int t = q0 + kb * 4 + r;
                if (t < T) {
                    const float v = o[mi][r];
                    const size_t oi = ((size_t)b * T + t) * DIM + h * 64 + mi * 16 + lr;
                    const unsigned short hh = f2bf(v);
                    Oh[oi] = hh;
                    Ol[oi] = f2bf(v - bf2f(hh));
                }
            }
    }
}

// ---------------- pruning decision (1 block) ----------------
__global__ void prune_k(const float* __restrict__ imp_bh, int* mask, float* state)
{
    __shared__ float imp[NP];
    __shared__ int smask[NP];
    __shared__ int s_Nnext;
    const int tid = threadIdx.x;
    if (tid < NP) {
        float s = 0.f;
        for (int r = 0; r < BSZ * NH; r++) s += imp_bh[(size_t)r * NP + tid];
        const int m = mask[1 + tid];
        smask[tid] = m;
        imp[tid] = m ? (s * (1.f / (BSZ * NH))) : 0.f;
    }
    __syncthreads();
    if (tid == 0) {
        float mass = 0.f;
        for (int j = 0; j < NP; j++) mass += imp[j];
        const float Nf = state[1];
        const float prev_mass = state[0];
        const int prev_valid = (int)state[2];
        float ent = 0.f;
        for (int j = 0; j < NP; j++) {
            if (smask[j]) {
                const float p = imp[j] / (mass + 1e-6f);
                ent -= p * logf(p + 1e-6f);
            }
        }
        const float rho = ent / logf(Nf);
        float kr = 1.f - 0.01f * rho * mass / (prev_mass + 1e-6f);
        kr = fminf(fmaxf(kr, 0.f), 1.f);
        if (!prev_valid) kr = 1.f;
        int Nn = (int)floorf(Nf * kr);
        if (Nn < 16) Nn = 16;
        const int Ni = (int)Nf;
        Nn = (Ni > 16) ? ((Nn < Ni) ? Nn : Ni) : Ni;
        state[0] = mass;
        state[1] = (float)Nn;
        state[2] = (Ni > 16) ? 1.f : 0.f;
        s_Nnext = Nn;
        mask[0] = 1;
    }
    __syncthreads();
    if (tid < NP) {
        const float kj = smask[tid] ? -imp[tid] : INFINITY;
        int rank = 0;
        for (int k = 0; k < NP; k++) {
            const float kk = smask[k] ? -imp[k] : INFINITY;
            rank += (kk < kj || (kk == kj && k < tid)) ? 1 : 0;
        }
        mask[1 + tid] = (rank < s_Nnext) ? 1 : 0;
    }
}

// ---------------- state init ----------------
__global__ void init_k(int* mask, float* state)
{
    const int t = threadIdx.x;
    if (t < T) mask[t] = 1;
    if (t == 0) {
        state[0] = 0.f;
        state[1] = (float)NP;
        state[2] = 0.f;
    }
}

// ---------------- fp32 GEMM for the tiny head (64x1000x768) ----------------
#define BM 128
#define BN 128
#define BK 8
__device__ __forceinline__ float4 load_b_guard(const float* wp, int ncol0, int N) {
    float4 r;
    r.x = (ncol0 + 0 < N) ? wp[0] : 0.f;
    r.y = (ncol0 + 1 < N) ? wp[1] : 0.f;
    r.z = (ncol0 + 2 < N) ? wp[2] : 0.f;
    r.w = (ncol0 + 3 < N) ? wp[3] : 0.f;
    return r;
}
__global__ __launch_bounds__(256, 2) void gemm_f32_k(
    const float* __restrict__ A, const float* __restrict__ W,
    const float* __restrict__ bias, float* C, int M, int N, int K)
{
    __shared__ float As[BK][BM];
    __shared__ float Bs[BK][BN];
    const int tid = threadIdx.x;
    const int m0 = blockIdx.x * BM, n0 = blockIdx.y * BN;
    const int tx = tid & 15, ty = tid >> 4;
    const int arow = tid >> 1, ak = (tid & 1) * 4;
    const int brow = tid >> 5, bcol = (tid & 31) * 4;
    const bool aval = (m0 + arow) < M;
    const float* Ap = A + (size_t)(m0 + arow) * K + ak;
    const float* Wp = W + (size_t)brow * N + n0 + bcol;
    const bool bfull = (n0 + BN) <= N;

    float acc[8][8];
#pragma unroll
    for (int i = 0; i < 8; i++)
#pragma unroll
        for (int j = 0; j < 8; j++) acc[i][j] = 0.f;

    float4 ar = aval ? ldg4(Ap) : make_float4(0.f, 0.f, 0.f, 0.f);
    float4 br = bfull ? ldg4(Wp) : load_b_guard(Wp, n0 + bcol, N);

    int k0 = 0;
    while (true) {
        __syncthreads();
        As[ak + 0][arow] = ar.x;
        As[ak + 1][arow] = ar.y;
        As[ak + 2][arow] = ar.z;
        As[ak + 3][arow] = ar.w;
        *reinterpret_cast<float4*>(&Bs[brow][bcol]) = br;
        __syncthreads();
        const int kn = k0 + BK;
        const bool more = kn < K;
        if (more) {
            ar = aval ? ldg4(Ap + kn) : make_float4(0.f, 0.f, 0.f, 0.f);
            const float* wp = Wp + (size_t)kn * N;
            br = bfull ? ldg4(wp) : load_b_guard(wp, n0 + bcol, N);
        }
#pragma unroll
        for (int kk = 0; kk < BK; kk++) {
            float a[8], bb[8];
            *reinterpret_cast<float4*>(&a[0]) = *reinterpret_cast<const float4*>(&As[kk][ty * 4]);
            *reinterpret_cast<float4*>(&a[4]) = *reinterpret_cast<const float4*>(&As[kk][64 + ty * 4]);
            *reinterpret_cast<float4*>(&bb[0]) = *reinterpret_cast<const float4*>(&Bs[kk][tx * 4]);
            *reinterpret_cast<float4*>(&bb[4]) = *reinterpret_cast<const float4*>(&Bs[kk][64 + tx * 4]);
#pragma unroll
            for (int i = 0; i < 8; i++)
#pragma unroll
                for (int j = 0; j < 8; j++) acc[i][j] += a[i] * bb[j];
        }
        if (!more) break;
        k0 = kn;
    }
#pragma unroll
    for (int i = 0; i < 8; i++) {
        const int m = m0 + (i < 4 ? ty * 4 + i : 64 + ty * 4 + (i - 4));
        if (m >= M) continue;
#pragma unroll
        for (int j = 0; j < 8; j++) {
            const int n = n0 + (j < 4 ? tx * 4 + j : 64 + tx * 4 + (j - 4));
            if (n >= N) continue;
            C[(size_t)m * N + n] = acc[i][j] + bias[n];
        }
    }
}

// ---------------- launch ----------------
extern "C" void kernel_launch(void* const* d_in, const int* in_sizes, int n_in,
                              void* d_out, int out_size, void* d_ws, size_t ws_size,
                              hipStream_t stream)
{
    const float* x_img   = (const float*)d_in[0];
    const float* cls_t   = (const float*)d_in[1];
    const float* pos_e   = (const float*)d_in[2];
    const float* patch_w = (const float*)d_in[3];
    const float* patch_b = (const float*)d_in[4];
    const float* ln1_g   = (const float*)d_in[5];
    const float* ln1_b   = (const float*)d_in[6];
    const float* qkv_w   = (const float*)d_in[7];
    const float* qkv_b   = (const float*)d_in[8];
    const float* proj_w  = (const float*)d_in[9];
    const float* proj_b  = (const float*)d_in[10];
    const float* ln2_g   = (const float*)d_in[11];
    const float* ln2_b   = (const float*)d_in[12];
    const float* fc1_w   = (const float*)d_in[13];
    const float* fc1_b   = (const float*)d_in[14];
    const float* fc2_w   = (const float*)d_in[15];
    const float* fc2_b   = (const float*)d_in[16];
    const float* norm_g  = (const float*)d_in[17];
    const float* norm_b  = (const float*)d_in[18];
    const float* head_w  = (const float*)d_in[19];
    const float* head_b  = (const float*)d_in[20];
    float* out = (float*)d_out;

    typedef unsigned short u16;
    const size_t SZX = (size_t)NTOK * DIM;          // 9,682,944
    const size_t QSZ = (size_t)BSZ * NH * QROWS * 64; // 10,223,616 per split buffer

    float* X  = (float*)d_ws;
    u16* Hh = (u16*)(X + SZX);
    u16* Hl = Hh + SZX;
    char* BIGc = (char*)(Hl + SZX);                 // NTOK*FFD*4 bytes
    u16* Wh = (u16*)(BIGc + (size_t)NTOK * FFD * 4);
    u16* Wl = Wh + (size_t)FFD * DIM;
    float* HC  = (float*)(Wl + (size_t)FFD * DIM);
    float* IMP = HC + (size_t)BSZ * DIM;
    int*   msk = (int*)(IMP + (size_t)BSZ * NH * NP);
    float* st  = (float*)(msk + 256);

    // BIG overlays (never simultaneously live):
    u16* Qh = (u16*)BIGc;       u16* Ql = Qh + QSZ;
    u16* Kh = Ql + QSZ;         u16* Kl = Kh + QSZ;
    u16* Vh = Kl + QSZ;         u16* Vl = Vh + QSZ;   // 6*QSZ*2B = 122.7MB
    u16* Gh = (u16*)BIGc;       u16* Gl = Gh + (size_t)NTOK * FFD; // 155MB
    u16* Ph = (u16*)BIGc;       u16* Pl = Ph + (size_t)NPATCH * DIM;

    init_k<<<1, 256, 0, stream>>>(msk, st);
    clspos_k<<<(BSZ * DIM + 255) / 256, 256, 0, stream>>>(X, cls_t, pos_e);

    // patch embed
    psplit_k<<<(NPATCH * 96 + 255) / 256, 256, 0, stream>>>(x_img, Ph, Pl);
    wsplit_k<<<dim3(DIM / 32, DIM / 32), 256, 0, stream>>>(patch_w, Wh, Wl, DIM, DIM);
    mgemm_k<3><<<dim3(NPATCH / 128, DIM / 128), 256, 0, stream>>>(
        Ph, Pl, Wh, Wl, patch_b, pos_e, X,
        nullptr, nullptr, nullptr, nullptr, nullptr, nullptr, NPATCH, DIM, DIM);

    const int gm = (NTOK + 127) / 128;  // 99
    for (int i = 0; i < DEPTH; i++) {
        ln_k<1><<<(NTOK + 3) / 4, 256, 0, stream>>>(X, ln1_g + i * DIM, ln1_b + i * DIM,
                                                    nullptr, Hh, Hl, NTOK, (size_t)DIM);
        wsplit_k<<<dim3(DIM / 32, (3 * DIM) / 32), 256, 0, stream>>>(
            qkv_w + (size_t)i * DIM * 3 * DIM, Wh, Wl, DIM, 3 * DIM);
        mgemm_k<4><<<dim3(gm, (3 * DIM) / 128), 256, 0, stream>>>(
            Hh, Hl, Wh, Wl, qkv_b + (size_t)i * 3 * DIM, nullptr, nullptr,
            Qh, Ql, Kh, Kl, Vh, Vl, NTOK, 3 * DIM, DIM);
        attn_k<<<BSZ * NH, 512, 0, stream>>>(Qh, Ql, Kh, Kl, Vh, Vl, Hh, Hl, msk, IMP);
        wsplit_k<<<dim3(DIM / 32, DIM / 32), 256, 0, stream>>>(
            proj_w + (size_t)i * DIM * DIM, Wh, Wl, DIM, DIM);
        mgemm_k<1><<<dim3(gm, DIM / 128), 256, 0, stream>>>(
            Hh, Hl, Wh, Wl, proj_b + (size_t)i * DIM, X, X,
            nullptr, nullptr, nullptr, nullptr, nullptr, nullptr, NTOK, DIM, DIM);
        ln_k<1><<<(NTOK + 3) / 4, 256, 0, stream>>>(X, ln2_g + i * DIM, ln2_b + i * DIM,
                                                    nullptr, Hh, Hl, NTOK, (size_t)DIM);
        wsplit_k<<<dim3(DIM / 32, FFD / 32), 256, 0, stream>>>(
            fc1_w + (size_t)i * DIM * FFD, Wh, Wl, DIM, FFD);
        mgemm_k<2><<<dim3(gm, FFD / 128), 256, 0, stream>>>(
            Hh, Hl, Wh, Wl, fc1_b + (size_t)i * FFD, nullptr, nullptr,
            Gh, Gl, nullptr, nullptr, nullptr, nullptr, NTOK, FFD, DIM);
        wsplit_k<<<dim3(FFD / 32, DIM / 32), 256, 0, stream>>>(
            fc2_w + (size_t)i * FFD * DIM, Wh, Wl, FFD, DIM);
        mgemm_k<1><<<dim3(gm, DIM / 128), 256, 0, stream>>>(
            Gh, Gl, Wh, Wl, fc2_b + (size_t)i * DIM, X, X,
            nullptr, nullptr, nullptr, nullptr, nullptr, nullptr, NTOK, DIM, FFD);
        prune_k<<<1, 256, 0, stream>>>(IMP, msk, st);
    }

    ln_k<0><<<16, 256, 0, stream>>>(X, norm_g, norm_b, HC, nullptr, nullptr,
                                    BSZ, (size_t)T * DIM);
    gemm_f32_k<<<dim3(1, (NC + 127) / 128), 256, 0, stream>>>(
        HC, head_w, head_b, out, BSZ, NC, DIM);
}